// Round 13
// baseline (201.150 us; speedup 1.0000x reference)
//
#include <hip/hip_runtime.h>
#include <hip/hip_bf16.h>

// Problem constants: N=20000 nodes, K=32 nbrs, C=128, H=256
#define NN    20000
#define KNN   32
#define CIN   128
#define HD    256
#define EE    (NN * KNN)        // 640000 edges
#define NT    20                // nodes per ec_main block (1 node per tile)
#define NBLK  (NN / NT)         // 1000 blocks
#define PZB   (NN / 32)         // 625 pz blocks

typedef __bf16 bf16x8_t __attribute__((ext_vector_type(8)));
typedef __bf16 bf16x4_t __attribute__((ext_vector_type(4)));
typedef float  f32x4_t  __attribute__((ext_vector_type(4)));

// LDS-only barrier: s_waitcnt lgkmcnt(0) + s_barrier, WITHOUT the vmcnt(0)
// drain __syncthreads() emits. The loop barrier only protects ldsH/ldsP.
__device__ __forceinline__ void barrier_lgkm() {
    asm volatile("s_waitcnt lgkmcnt(0)\n\ts_barrier" ::: "memory");
}

// Fused prep (round-13: 2 kernels total — each launch boundary measured
// ~20-25 µs; wprep folded in, w1g intermediate deleted).
// blocks 0..624: per-node precompute of both GEMM1 halves (senders repeat,
//   so the 42 GF edge-GEMM1 collapses to 2.6 GF of node-GEMM):
//     Pq[n][f] = sum_k X[n][k]*(W1a-W1b)[k][f] + b1[f]   (fp32)
//     Zq[n][f] = sum_k X[n][k]*W1b[k][f]                 (bf16)
//   W1' fragments built inline from fp32 W1 (L2-hot). The P half caches its
//   W1b loads in 32 VGPRs so the Z half needs ZERO weight loads (128
//   loads/wave total vs round-5's 192 — that version's ~10 µs penalty).
//   Zero-LDS (round-10): MFMA C-layout stores are already coalesced.
// blocks 625..752: w2t[n*256+k] = bf16(W2[k][n])  (read only by ec_main).
__global__ __launch_bounds__(512, 1) void ec_pz(
    const float* __restrict__ nf, const float* __restrict__ W1,
    const float* __restrict__ W2, const float* __restrict__ b1,
    float* __restrict__ Pq, __bf16* __restrict__ Zq, __bf16* __restrict__ w2t)
{
    const int bid = blockIdx.x;
    const int tid = threadIdx.x;

    if (bid >= PZB) {                                // W2 transpose tail blocks
        int idx = (bid - PZB) * 512 + tid;           // 0..65535
        int k = idx >> 8, n = idx & 255;
        w2t[n * 256 + k] = (__bf16)W2[k * 256 + n];
        return;
    }

    const int lane = tid & 63;
    const int wave = tid >> 6;
    const int qrow = lane >> 4;
    const int lcol = lane & 15;
    const int fsl  = wave * 32;

    // node features for this block's 32 nodes (lane-col = node), fp32 -> bf16
    bf16x8_t xv[2][4];
#pragma unroll
    for (int ni = 0; ni < 2; ++ni) {
        const float* row = nf + (size_t)(bid * 32 + ni * 16 + lcol) * CIN;
#pragma unroll
        for (int c = 0; c < 4; ++c) {
            f32x4_t a = *(const f32x4_t*)(row + c * 32 + qrow * 8);
            f32x4_t b = *(const f32x4_t*)(row + c * 32 + qrow * 8 + 4);
            bf16x8_t x;
#pragma unroll
            for (int j = 0; j < 4; ++j) { x[j] = (__bf16)a[j]; x[j + 4] = (__bf16)b[j]; }
            xv[ni][c] = x;
        }
    }

    float4 bias1[2];
#pragma unroll
    for (int mi = 0; mi < 2; ++mi)
        bias1[mi] = *(const float4*)(b1 + fsl + mi * 16 + qrow * 4);

    bf16x8_t wzc[4][2];   // cached W1b fragments (filled in P half, used in Z half)

    // ---- P half: wy = bf16(W1a - W1b) built inline; cache bf16(W1b) ----
    {
        f32x4_t ay[2][2];
#pragma unroll
        for (int mi = 0; mi < 2; ++mi)
#pragma unroll
            for (int ni = 0; ni < 2; ++ni)
                ay[mi][ni] = (f32x4_t){0.f, 0.f, 0.f, 0.f};
#pragma unroll
        for (int kt = 0; kt < 4; ++kt) {
            const float* wrow = W1 + (size_t)(kt * 32 + qrow * 8) * 256;
            bf16x8_t wy[2];
#pragma unroll
            for (int mi = 0; mi < 2; ++mi) {
                const int col = fsl + mi * 16 + lcol;
                bf16x8_t wa, wb;
#pragma unroll
                for (int j = 0; j < 8; ++j) {
                    float va = wrow[(size_t)j * 256 + col];
                    float vb = wrow[(size_t)(j + 128) * 256 + col];
                    wa[j] = (__bf16)(va - vb);
                    wb[j] = (__bf16)vb;
                }
                wy[mi] = wa;
                wzc[kt][mi] = wb;
            }
#pragma unroll
            for (int mi = 0; mi < 2; ++mi)
#pragma unroll
                for (int ni = 0; ni < 2; ++ni)
                    ay[mi][ni] = __builtin_amdgcn_mfma_f32_16x16x32_bf16(
                        wy[mi], xv[ni][kt], ay[mi][ni], 0, 0, 0);
        }
        // C-layout: row = feature fsl+mi*16+qrow*4+r, col = node ni*16+lcol
#pragma unroll
        for (int mi = 0; mi < 2; ++mi)
#pragma unroll
            for (int ni = 0; ni < 2; ++ni) {
                f32x4_t v = ay[mi][ni];
                v[0] += bias1[mi].x; v[1] += bias1[mi].y;
                v[2] += bias1[mi].z; v[3] += bias1[mi].w;
                *(f32x4_t*)(Pq + (size_t)(bid * 32 + ni * 16 + lcol) * 256
                               + fsl + mi * 16 + qrow * 4) = v;
            }
    }

    // ---- Z half: uses cached W1b fragments, zero weight loads ----
    {
        f32x4_t az[2][2];
#pragma unroll
        for (int mi = 0; mi < 2; ++mi)
#pragma unroll
            for (int ni = 0; ni < 2; ++ni)
                az[mi][ni] = (f32x4_t){0.f, 0.f, 0.f, 0.f};
#pragma unroll
        for (int kt = 0; kt < 4; ++kt)
#pragma unroll
            for (int mi = 0; mi < 2; ++mi)
#pragma unroll
                for (int ni = 0; ni < 2; ++ni)
                    az[mi][ni] = __builtin_amdgcn_mfma_f32_16x16x32_bf16(
                        wzc[kt][mi], xv[ni][kt], az[mi][ni], 0, 0, 0);
#pragma unroll
        for (int mi = 0; mi < 2; ++mi)
#pragma unroll
            for (int ni = 0; ni < 2; ++ni) {
                f32x4_t v = az[mi][ni];
                bf16x4_t b = { (__bf16)v[0], (__bf16)v[1], (__bf16)v[2], (__bf16)v[3] };
                *(bf16x4_t*)(Zq + (size_t)(bid * 32 + ni * 16 + lcol) * 256
                                + fsl + mi * 16 + qrow * 4) = b;
            }
    }
}

// One tile (unchanged from round 12 — proven 115-117 µs): GEMM2(t) reading
// Hr, H(t+1)-assemble fused into kt=4..7, Z(tt+2) gather issued post-kt-loop
// and left in flight across the lgkm-only barrier.
__device__ __forceinline__ void tile_body(
    const int tt, const __bf16* __restrict__ Hr, __bf16* __restrict__ Hw,
    bf16x8_t (&zf)[4],
    const float* __restrict__ lP, const __bf16* __restrict__ Zq,
    const int* __restrict__ senders, float* __restrict__ out,
    const bf16x8_t (&w2f)[8][4], const float (&bias2)[4],
    int& sn, const int n0, const int qrow, const int lcol,
    const int e5, const int fb, const int ktb, const int fsl)
{
    const bool pre = (tt + 1 < NT);
    const int na = pre ? tt + 1 : 0;
    const float* pfA = lP + na * 256 + fb;

    f32x4_t acc2[2][4];
#pragma unroll
    for (int mi = 0; mi < 2; ++mi)
#pragma unroll
        for (int ni = 0; ni < 4; ++ni)
            acc2[mi][ni] = (f32x4_t){0.f, 0.f, 0.f, 0.f};

    // ---- GEMM2 (K=256) with assemble chunks fused into kt=4..7 ----
#pragma unroll
    for (int kt = 0; kt < 8; ++kt) {
        bf16x8_t af[2];
#pragma unroll
        for (int mi = 0; mi < 2; ++mi)
            af[mi] = *(const bf16x8_t*)(Hr +
                (size_t)((kt * 4 + qrow) * 32 + mi * 16 + lcol) * 8);
#pragma unroll
        for (int mi = 0; mi < 2; ++mi)
#pragma unroll
            for (int ni = 0; ni < 4; ++ni)
                acc2[mi][ni] = __builtin_amdgcn_mfma_f32_16x16x32_bf16(
                    af[mi], w2f[kt][ni], acc2[mi][ni], 0, 0, 0);
        if (kt >= 4 && pre) {
            const int c = kt - 4;             // compile-time in unrolled loop
            f32x4_t p0 = *(const f32x4_t*)(pfA + c * 8);
            f32x4_t p1 = *(const f32x4_t*)(pfA + c * 8 + 4);
            bf16x8_t h;
#pragma unroll
            for (int j = 0; j < 4; ++j) {
                h[j]     = (__bf16)fmaxf(p0[j] + (float)zf[c][j],     0.f);
                h[j + 4] = (__bf16)fmaxf(p1[j] + (float)zf[c][j + 4], 0.f);
            }
            *(bf16x8_t*)(Hw + (size_t)((ktb * 4 + c) * 32 + e5) * 8) = h;
        }
    }

    // ---- issue gather Z(tt+2) into zf (consumed at tile tt+1's kt>=4);
    //      crosses the lgkm-only barrier still in flight ----
    if (tt + 2 < NT) {
        const __bf16* zb = Zq + (size_t)sn * HD + fb;
#pragma unroll
        for (int c = 0; c < 4; ++c)
            zf[c] = *(const bf16x8_t*)(zb + c * 8);
    }
    if (tt + 3 < NT) sn = senders[(n0 + tt + 3) * KNN + e5];

    // ---- epilogue: max over the node's 32 edges, +b2, store ----
#pragma unroll
    for (int ni = 0; ni < 4; ++ni) {
        float mx = -3.402823466e38f;
#pragma unroll
        for (int mi = 0; mi < 2; ++mi)
#pragma unroll
            for (int r = 0; r < 4; ++r)
                mx = fmaxf(mx, acc2[mi][ni][r]);
        mx = fmaxf(mx, __shfl_xor(mx, 16, 64));
        mx = fmaxf(mx, __shfl_xor(mx, 32, 64));
        if (qrow == 0)
            out[(size_t)(n0 + tt) * HD + fsl + ni * 16 + lcol] = mx + bias2[ni];
    }

    barrier_lgkm();   // publishes Hw (ds ops drained); Z-gather stays in flight
    // hazards: Hw's previous readers (GEMM2(tt-1)) completed their ds_reads
    // before barrier(tt-1) (lgkmcnt(0) drains reads too); this body's writes
    // run after it. Hw's new readers (GEMM2(tt+1)) run after this barrier.
}

// Main (byte-identical to round 12 — 2 blocks/CU, 2 waves/SIMD, 124 arch +
// 128 AGPR, no spill; ≤124-arch budget is a hard guard).
__global__ __launch_bounds__(256, 1) void ec_main(
    const __bf16* __restrict__ Zq,       // [NN][HD] bf16
    const int*   __restrict__ senders,   // [EE]
    const float* __restrict__ Pq,        // [NN][HD] fp32 (b1 folded in)
    const __bf16* __restrict__ w2t,      // [256 n][256 k]
    const float* __restrict__ b2,
    float* __restrict__ out)             // [NN][HD] fp32
{
    __shared__ __attribute__((aligned(16))) __bf16 ldsH0[8192];     // 16 KB H even
    __shared__ __attribute__((aligned(16))) __bf16 ldsH1[8192];     // 16 KB H odd
    __shared__ __attribute__((aligned(16))) float  ldsP[NT * 256];  // 20 KB fp32 P'

    const int tid  = threadIdx.x;
    const int lane = tid & 63;
    const int wave = tid >> 6;           // 0..3
    const int qrow = lane >> 4;
    const int lcol = lane & 15;
    const int blk  = blockIdx.x;
    const int fsl  = wave * 64;          // this wave's feature slice (assemble + GEMM2)
    const int e5   = lane & 31;          // edge id for gather/senders
    const int half = lane >> 5;          // feature half within slice (assemble)
    const int fb   = fsl + half * 32;    // assemble feature base (32-aligned)
    const int ktb  = fb >> 5;            // frag kt for assemble writes
    const int n0   = blk * NT;

    // ---- cooperative P' load: NT rows x 256 fp32 ----
    {
        const float4* src = (const float4*)(Pq + (size_t)n0 * 256);
        float4* dst = (float4*)ldsP;
#pragma unroll
        for (int i = 0; i < 5; ++i)
            dst[tid + i * 256] = src[tid + i * 256];
    }

    // ---- sender indices for tiles 0,1,2; gather Z(0) ----
    int s0  = senders[(n0 + 0) * KNN + e5];
    int sn1 = senders[(n0 + 1) * KNN + e5];
    int sn  = senders[(n0 + 2) * KNN + e5];

    bf16x8_t zf[4];
    {
        const __bf16* zb = Zq + (size_t)s0 * HD + fb;
#pragma unroll
        for (int c = 0; c < 4; ++c)
            zf[c] = *(const bf16x8_t*)(zb + c * 8);
    }

    // ---- register-resident W2 slice (64 features): 128 regs ----
    bf16x8_t w2f[8][4];
#pragma unroll
    for (int kt = 0; kt < 8; ++kt)
#pragma unroll
        for (int ni = 0; ni < 4; ++ni)
            w2f[kt][ni] = *(const bf16x8_t*)(w2t + (size_t)(fsl + ni * 16 + lcol) * 256
                                                 + kt * 32 + qrow * 8);
    float bias2[4];
#pragma unroll
    for (int ni = 0; ni < 4; ++ni)
        bias2[ni] = b2[fsl + ni * 16 + lcol];

    __syncthreads();   // ldsP ready (full drain fine here: Z(0) is needed now)

    // ---- assemble H(0) -> ldsH0: h = relu(P'[node0] + Z(0)) ----
    {
        const float* pf = ldsP + 0 * 256 + fb;
#pragma unroll
        for (int c = 0; c < 4; ++c) {
            f32x4_t p0 = *(const f32x4_t*)(pf + c * 8);
            f32x4_t p1 = *(const f32x4_t*)(pf + c * 8 + 4);
            bf16x8_t h;
#pragma unroll
            for (int j = 0; j < 4; ++j) {
                h[j]     = (__bf16)fmaxf(p0[j] + (float)zf[c][j],     0.f);
                h[j + 4] = (__bf16)fmaxf(p1[j] + (float)zf[c][j + 4], 0.f);
            }
            *(bf16x8_t*)(ldsH0 + (size_t)((ktb * 4 + c) * 32 + e5) * 8) = h;
        }
    }

    // ---- issue gather Z(1) (consumed at tile 0's kt>=4); crosses barrier ----
    {
        const __bf16* zb = Zq + (size_t)sn1 * HD + fb;
#pragma unroll
        for (int c = 0; c < 4; ++c)
            zf[c] = *(const bf16x8_t*)(zb + c * 8);
    }

    barrier_lgkm();    // ldsH0 published; Z(1) stays in flight

#pragma unroll 1
    for (int tp = 0; tp < NT; tp += 2) {
        tile_body(tp,     ldsH0, ldsH1, zf, ldsP, Zq, senders, out,
                  w2f, bias2, sn, n0, qrow, lcol, e5, fb, ktb, fsl);
        tile_body(tp + 1, ldsH1, ldsH0, zf, ldsP, Zq, senders, out,
                  w2f, bias2, sn, n0, qrow, lcol, e5, fb, ktb, fsl);
    }
}

extern "C" void kernel_launch(void* const* d_in, const int* in_sizes, int n_in,
                              void* d_out, int out_size, void* d_ws, size_t ws_size,
                              hipStream_t stream) {
    const float* nf      = (const float*)d_in[0];
    const int*   senders = (const int*)d_in[1];
    // d_in[2] = receivers: implicit (repeat(arange(N), K)), unused
    const float* W1 = (const float*)d_in[3];
    const float* b1 = (const float*)d_in[4];
    const float* W2 = (const float*)d_in[5];
    const float* b2 = (const float*)d_in[6];

    __bf16* w2t = (__bf16*)d_ws;                 // 128 KB [n][k] bf16 W2^T
    __bf16* Zq  = w2t + 256 * 256;               // 10.24 MB bf16 Z = X*W1b
    float*  Pq  = (float*)(Zq + (size_t)NN * HD);// 20.48 MB fp32 P' = X*(W1a-W1b)+b1

    ec_pz<<<PZB + 128, 512, 0, stream>>>(nf, W1, W2, b1, Pq, Zq, w2t);
    ec_main<<<NBLK, 256, 0, stream>>>(Zq, senders, Pq, w2t, b2, (float*)d_out);
}